// Round 12
// baseline (63.539 us; speedup 1.0000x reference)
//
#include <hip/hip_runtime.h>

// Chamfer distance, fp32 brute force, row-min only (537M pairs), VALU-bound.
// rows 0..32767    : predict points (b = r>>13), cols = target[b]
// rows 32768..65535: target points,              cols = predict[b]
// Per row: min over 8192 cols of (||t||^2 - 2 p.t), then + ||p||^2 (reduce).
// out = (sum over all 65536 rows) / 32768.
//
// Columns are wave-uniform -> explicit s_load_dwordx4 batches (8 cols = 32
// SGPRs) with the single s_waitcnt lgkmcnt(0) INSIDE the asm block (SMEM
// completes OUT OF ORDER — counted lgkmcnt(N) on s_load returned inf in R8).
// Zero LDS, zero per-lane VMEM intended in the hot loop.
// ROW-STATE PINNING: R9 (cap 64) gave VGPR=20, R11 (cap 128) gave VGPR=32 —
// the backend REMATERIALIZES qx/qy/qz by re-loading packed[] (L2-hit, so
// invisible in FETCH_SIZE) every iteration instead of keeping 32 VGPRs
// live. launch_bounds can't stop the remat heuristic; the empty
// asm volatile "+v" pins at the loop top make each value a register def,
// killing the remat source. Expect VGPR 48-80 and ~26-33us if the
// 3.5-VALU/pair issue model is right.
// Cross-chunk combine: deterministic atomicMin on monotone uint keys,
// per-lane distinct addresses (coalesced).

#define NPTS   8192
#define HALF   32768            // 4 * NPTS
#define NROWS  65536
#define P      8                // rows per thread (32 VGPR row state)
#define RPB    2048             // rows per block = 256 * P
#define NRB    32               // NROWS / RPB
#define NCH    64               // col chunks -> 2048 blocks = 8/CU
#define CW     (NPTS / NCH)     // 128 cols per chunk

typedef float sfloat4 __attribute__((ext_vector_type(4)));

__device__ __forceinline__ void min3t(float& a, float b, float c) {
    asm("v_min3_f32 %0, %0, %1, %2" : "+v"(a) : "v"(b), "v"(c));
}
__device__ __forceinline__ unsigned int fkey(float f) {
    unsigned int b = __float_as_uint(f);
    return b ^ (0x80000000u | (unsigned int)((int)b >> 31));
}
__device__ __forceinline__ float funkey(unsigned int k) {
    unsigned int b = (k & 0x80000000u) ? (k ^ 0x80000000u) : ~k;
    return __uint_as_float(b);
}

// keep 8 floats register-resident: each "+v" is a def -> remat-from-memory
// is no longer a legal source for later uses (rule #17 hammer).
#define PIN8(a) asm volatile("" : "+v"(a[0]), "+v"(a[1]), "+v"(a[2]), "+v"(a[3]), \
                                  "+v"(a[4]), "+v"(a[5]), "+v"(a[6]), "+v"(a[7]))

__global__ __launch_bounds__(256) void pack_kernel(
    const float* __restrict__ predict, const float* __restrict__ target,
    float4* __restrict__ packed, unsigned int* __restrict__ rowmin)
{
    int r = blockIdx.x * 256 + threadIdx.x;
    const float* src = (r < HALF) ? (predict + (size_t)r * 3)
                                  : (target + (size_t)(r - HALF) * 3);
    float x = src[0], y = src[1], z = src[2];
    float nrm = fmaf(x, x, fmaf(y, y, z * z));
    packed[r] = make_float4(x, y, z, nrm);
    rowmin[r] = 0xFFFFFFFFu;                  // +inf key
}

// 2 columns folded into the P row-mins: 6 fma + 1 min3 per row
#define COLPAIR(ta, tb) do {                                                  \
    float twA = (ta).w, twB = (tb).w;                                         \
    _Pragma("unroll")                                                         \
    for (int j = 0; j < P; ++j) {                                             \
        float sA = fmaf(qx[j], (ta).x, fmaf(qy[j], (ta).y, fmaf(qz[j], (ta).z, twA))); \
        float sB = fmaf(qx[j], (tb).x, fmaf(qy[j], (tb).y, fmaf(qz[j], (tb).z, twB))); \
        min3t(mn[j], sA, sB);                                                 \
    }                                                                         \
} while (0)

__global__ __launch_bounds__(256, 4) void minpart_kernel(
    const float4* __restrict__ packed, unsigned int* __restrict__ rowmin)
{
    const int rb   = blockIdx.x / NCH;
    const int cb   = blockIdx.x % NCH;
    const int row0 = rb * RPB;
    const bool sideA = (row0 < HALF);
    const int local = sideA ? row0 : row0 - HALF;
    const int b = local >> 13;                // / NPTS
    const float4* __restrict__ cbase =
        packed + ((sideA ? HALF : 0) + (b << 13) + cb * CW);
    const int tid = threadIdx.x;

    float qx[P], qy[P], qz[P], mn[P];
    #pragma unroll
    for (int j = 0; j < P; ++j) {
        float4 p = packed[row0 + tid + j * 256];
        qx[j] = -2.0f * p.x; qy[j] = -2.0f * p.y; qz[j] = -2.0f * p.z;
        mn[j] = 3.4e38f;
    }

    #pragma unroll 1
    for (int g = 0; g < CW / 8; ++g) {
        PIN8(qx); PIN8(qy); PIN8(qz);         // force row state resident

        const float4* cp = cbase + g * 8;
        sfloat4 t0, t1, t2, t3, t4, t5, t6, t7;
        asm volatile(
            "s_load_dwordx4 %0, %8, 0x0\n\t"
            "s_load_dwordx4 %1, %8, 0x10\n\t"
            "s_load_dwordx4 %2, %8, 0x20\n\t"
            "s_load_dwordx4 %3, %8, 0x30\n\t"
            "s_load_dwordx4 %4, %8, 0x40\n\t"
            "s_load_dwordx4 %5, %8, 0x50\n\t"
            "s_load_dwordx4 %6, %8, 0x60\n\t"
            "s_load_dwordx4 %7, %8, 0x70\n\t"
            "s_waitcnt lgkmcnt(0)"
            : "=s"(t0), "=s"(t1), "=s"(t2), "=s"(t3),
              "=s"(t4), "=s"(t5), "=s"(t6), "=s"(t7)
            : "s"(cp));

        COLPAIR(t0, t1);
        COLPAIR(t2, t3);
        COLPAIR(t4, t5);
        COLPAIR(t6, t7);
    }

    #pragma unroll
    for (int j = 0; j < P; ++j)
        atomicMin(&rowmin[row0 + tid + j * 256], fkey(mn[j]));
}

__global__ __launch_bounds__(256) void reduce_kernel(
    const float4* __restrict__ packed, const unsigned int* __restrict__ rowmin,
    float* __restrict__ blockSums)
{
    int r = blockIdx.x * 256 + threadIdx.x;
    float val = funkey(rowmin[r]) + packed[r].w;   // + own ||.||^2

    __shared__ float red[256];
    red[threadIdx.x] = val;
    __syncthreads();
    for (int s = 128; s > 0; s >>= 1) {
        if (threadIdx.x < s) red[threadIdx.x] += red[threadIdx.x + s];
        __syncthreads();
    }
    if (threadIdx.x == 0) blockSums[blockIdx.x] = red[0];
}

__global__ __launch_bounds__(256) void final_kernel(
    const float* __restrict__ blockSums, float* __restrict__ out)
{
    __shared__ float red[256];
    red[threadIdx.x] = blockSums[threadIdx.x];
    __syncthreads();
    for (int s = 128; s > 0; s >>= 1) {
        if (threadIdx.x < s) red[threadIdx.x] += red[threadIdx.x + s];
        __syncthreads();
    }
    if (threadIdx.x == 0) out[0] = red[0] * (1.0f / (float)HALF);
}

extern "C" void kernel_launch(void* const* d_in, const int* in_sizes, int n_in,
                              void* d_out, int out_size, void* d_ws, size_t ws_size,
                              hipStream_t stream)
{
    const float* predict = (const float*)d_in[0];
    const float* target  = (const float*)d_in[1];
    float* out = (float*)d_out;

    char* ws = (char*)d_ws;
    float4*       packed    = (float4*)ws;                              // 1 MB
    unsigned int* rowmin    = (unsigned int*)(ws + (size_t)NROWS * 16); // 256 KB
    float*        blockSums = (float*)(ws + (size_t)NROWS * 16
                                          + (size_t)NROWS * 4);         // 1 KB

    pack_kernel   <<<NROWS / 256, 256, 0, stream>>>(predict, target, packed, rowmin);
    minpart_kernel<<<NRB * NCH,   256, 0, stream>>>(packed, rowmin);
    reduce_kernel <<<NROWS / 256, 256, 0, stream>>>(packed, rowmin, blockSums);
    final_kernel  <<<1,           256, 0, stream>>>(blockSums, out);
}